// Round 3
// baseline (659.916 us; speedup 1.0000x reference)
//
#include <hip/hip_runtime.h>
#include <math.h>

#define E_TOTAL 1600000
#define NN 100000
#define NG 128
#define FF 64
#define NCHUNK (E_TOTAL / 4)      // 400000 four-edge chunks
#define MAXSTRAD 2048

// ---------------- init: zero T, den, nodeg, hg, scount ----------------
__global__ __launch_bounds__(256) void init_kernel(
        float* __restrict__ T, float* __restrict__ den,
        int* __restrict__ nodeg, float* __restrict__ hg,
        int* __restrict__ scount) {
    int i = blockIdx.x * blockDim.x + threadIdx.x;
    if (i < NN * 64) T[i] = 0.0f;
    if (i < NN) { den[i] = 0.0f; nodeg[i] = 0; }
    if (i < NG * FF) hg[i] = 0.0f;
    if (i == 0) *scount = 0;
}

// segment flush: reduce acc (features, mod-4-edge partials) + dacc across
// lane groups, atomically commit to T[d], den[d], nodeg[d].
__device__ __forceinline__ void seg_flush(float4& acc, float& dacc,
        int cur_d, int cur_g, int lane,
        float* __restrict__ T, float* __restrict__ den,
        int* __restrict__ nodeg) {
    float ax = acc.x, ay = acc.y, az = acc.z, aw = acc.w, dd = dacc;
    ax += __shfl_xor(ax, 16); ay += __shfl_xor(ay, 16);
    az += __shfl_xor(az, 16); aw += __shfl_xor(aw, 16);
    dd += __shfl_xor(dd, 16);
    ax += __shfl_xor(ax, 32); ay += __shfl_xor(ay, 32);
    az += __shfl_xor(az, 32); aw += __shfl_xor(aw, 32);
    dd += __shfl_xor(dd, 32);
    if (lane < 16) {
        float* p = T + (size_t)cur_d * 64 + lane * 4;
        atomicAdd(p + 0, ax); atomicAdd(p + 1, ay);
        atomicAdd(p + 2, az); atomicAdd(p + 3, aw);
    } else if (lane == 16) {
        atomicAdd(&den[cur_d], dd);
    } else if (lane == 17) {
        atomicMax(&nodeg[cur_d], cur_g);
    }
    acc.x = acc.y = acc.z = acc.w = 0.0f;
    dacc = 0.0f;
}

// ---------------- pass1: single feats pass ----------------
// dot -> leakyrelu -> exp (bounded s, no max-sub needed) -> ex store,
// den[d] += ex, T[d] += feats*ex, straddle-edge detection.
// Wave owns contiguous chunk range; 4 edges/chunk, lane=(edge q, feat quad sl).
__global__ __launch_bounds__(256) void pass1_kernel(
        const float4* __restrict__ feats4, const float4* __restrict__ W4,
        const float* __restrict__ b, const int* __restrict__ dst,
        const int* __restrict__ gid,
        float* __restrict__ exbuf, float* __restrict__ den,
        float* __restrict__ T, int* __restrict__ nodeg,
        int* __restrict__ scount, int* __restrict__ slist) {
    int tid  = blockIdx.x * blockDim.x + threadIdx.x;
    int lane = threadIdx.x & 63;
    int wave = tid >> 6;
    int nw   = (gridDim.x * blockDim.x) >> 6;
    int cpw  = (NCHUNK + nw - 1) / nw;
    int c0 = wave * cpw;
    if (c0 >= NCHUNK) return;
    int c1 = min(c0 + cpw, NCHUNK);
    int q = lane >> 4, sl = lane & 15;
    float4 w = W4[sl];
    float bias = b[0];

    int cur_d, cur_g;
    if (c0 == 0) { cur_d = -1; cur_g = -1; }
    else { cur_d = dst[c0 * 4 - 1]; cur_g = gid[c0 * 4 - 1]; }
    float4 acc = {0.f, 0.f, 0.f, 0.f};
    float dacc = 0.0f;

    // prefetch first chunk
    float4 v = feats4[(size_t)c0 * 64 + lane];
    int d = dst[c0 * 4 + q];
    int g = gid[c0 * 4 + q];

    for (int c = c0; c < c1; ++c) {
        float4 cv = v; int cd = d, cg = g;
        if (c + 1 < c1) {                       // prefetch next chunk
            v = feats4[(size_t)(c + 1) * 64 + lane];
            d = dst[(c + 1) * 4 + q];
            g = gid[(c + 1) * 4 + q];
        }
        float dq = cv.x * w.x + cv.y * w.y + cv.z * w.z + cv.w * w.w;
        dq += __shfl_xor(dq, 1); dq += __shfl_xor(dq, 2);
        dq += __shfl_xor(dq, 4); dq += __shfl_xor(dq, 8);   // all 16 lanes get sum
        float s = dq + bias;
        s = s > 0.0f ? s : 0.01f * s;           // LeakyReLU
        float ex = __expf(s);
        if (sl == 0) exbuf[c * 4 + q] = ex;

        int d0 = __builtin_amdgcn_readfirstlane(cd);
        int g0 = __builtin_amdgcn_readfirstlane(cg);
        if (__ballot(cd != d0 || cg != g0) == 0ULL) {      // uniform chunk (~70-75%+)
            if (d0 != cur_d) {
                if (cur_d >= 0) seg_flush(acc, dacc, cur_d, cur_g, lane, T, den, nodeg);
                cur_d = d0; cur_g = g0;
            } else if (g0 != cur_g) {           // graph boundary inside node segment
                if (lane == 0) {
                    int idx = atomicAdd(scount, 1);
                    if (idx < MAXSTRAD) slist[idx] = c * 4;
                }
                cur_g = g0;
            }
            acc.x += cv.x * ex; acc.y += cv.y * ex;
            acc.z += cv.z * ex; acc.w += cv.w * ex;
            dacc += (sl == 0) ? ex : 0.0f;
        } else {                                 // boundary chunk: per-edge subphases
            #pragma unroll
            for (int qq = 0; qq < 4; ++qq) {
                int dqq = __shfl(cd, qq * 16);
                int gqq = __shfl(cg, qq * 16);
                if (dqq != cur_d) {
                    if (cur_d >= 0) seg_flush(acc, dacc, cur_d, cur_g, lane, T, den, nodeg);
                    cur_d = dqq; cur_g = gqq;
                } else if (gqq != cur_g) {
                    if (lane == 0) {
                        int idx = atomicAdd(scount, 1);
                        if (idx < MAXSTRAD) slist[idx] = c * 4 + qq;
                    }
                    cur_g = gqq;
                }
                float m = (q == qq) ? ex : 0.0f;
                acc.x += cv.x * m; acc.y += cv.y * m;
                acc.z += cv.z * m; acc.w += cv.w * m;
                dacc += (sl == 0) ? m : 0.0f;
            }
        }
    }
    if (cur_d >= 0) seg_flush(acc, dacc, cur_d, cur_g, lane, T, den, nodeg);
}

// ---------------- pass2a: hg[g] += T[d]/den[d], double accumulators ----------------
__global__ __launch_bounds__(256) void pass2a_kernel(
        const float4* __restrict__ T4, const float* __restrict__ den,
        const int* __restrict__ nodeg, float* __restrict__ hg) {
    const int NCH = NN / 4;                     // 25000 node-chunks
    int tid  = blockIdx.x * blockDim.x + threadIdx.x;
    int lane = threadIdx.x & 63;
    int wave = tid >> 6;
    int nw   = (gridDim.x * blockDim.x) >> 6;
    int cpw  = (NCH + nw - 1) / nw;
    int c0 = wave * cpw;
    if (c0 >= NCH) return;
    int c1 = min(c0 + cpw, NCH);
    int q = lane >> 4;
    double ax = 0, ay = 0, az = 0, aw = 0;
    int cur_g = -1;

    for (int c = c0; c < c1; ++c) {
        int node = c * 4 + q;
        float4 tv = T4[(size_t)c * 64 + lane];
        float dn = den[node];
        int g = nodeg[node];
        float inv = dn > 0.0f ? 1.0f / dn : 0.0f;  // absent node guard
        int g0 = __builtin_amdgcn_readfirstlane(g);
        bool uni = (__ballot(g != g0) == 0ULL);
        if (uni && g0 == cur_g) {
            ax += (double)(tv.x * inv); ay += (double)(tv.y * inv);
            az += (double)(tv.z * inv); aw += (double)(tv.w * inv);
        } else {
            #pragma unroll
            for (int qq = 0; qq < 4; ++qq) {
                int gqq = __shfl(g, qq * 16);
                if (gqq != cur_g) {
                    if (cur_g >= 0) {
                        double bx = ax, by = ay, bz = az, bw = aw;
                        bx += __shfl_xor(bx, 16); by += __shfl_xor(by, 16);
                        bz += __shfl_xor(bz, 16); bw += __shfl_xor(bw, 16);
                        bx += __shfl_xor(bx, 32); by += __shfl_xor(by, 32);
                        bz += __shfl_xor(bz, 32); bw += __shfl_xor(bw, 32);
                        if (lane < 16) {
                            float* p = hg + cur_g * 64 + lane * 4;
                            atomicAdd(p + 0, (float)bx); atomicAdd(p + 1, (float)by);
                            atomicAdd(p + 2, (float)bz); atomicAdd(p + 3, (float)bw);
                        }
                        ax = ay = az = aw = 0;
                    }
                    cur_g = gqq;
                }
                float m = (q == qq) ? inv : 0.0f;
                ax += (double)(tv.x * m); ay += (double)(tv.y * m);
                az += (double)(tv.z * m); aw += (double)(tv.w * m);
            }
        }
    }
    if (cur_g >= 0) {
        ax += __shfl_xor(ax, 16); ay += __shfl_xor(ay, 16);
        az += __shfl_xor(az, 16); aw += __shfl_xor(aw, 16);
        ax += __shfl_xor(ax, 32); ay += __shfl_xor(ay, 32);
        az += __shfl_xor(az, 32); aw += __shfl_xor(aw, 32);
        if (lane < 16) {
            float* p = hg + cur_g * 64 + lane * 4;
            atomicAdd(p + 0, (float)ax); atomicAdd(p + 1, (float)ay);
            atomicAdd(p + 2, (float)az); atomicAdd(p + 3, (float)aw);
        }
    }
}

// ---------------- pass2b: fix graph-straddling node segments ----------------
// pass2a credited all of T[d] to g1 = max graph (atomicMax). Move the
// pre-boundary portion to g0. One wave per record; lane = feature.
__global__ __launch_bounds__(256) void pass2b_kernel(
        const float* __restrict__ feats, const float* __restrict__ exbuf,
        const float* __restrict__ den, const int* __restrict__ dst,
        const int* __restrict__ gid, const int* __restrict__ scount,
        const int* __restrict__ slist, float* __restrict__ hg) {
    int nrec = *scount; if (nrec > MAXSTRAD) nrec = MAXSTRAD;
    int lane = threadIdx.x & 63;
    int wave = (blockIdx.x * blockDim.x + threadIdx.x) >> 6;
    int nw   = (gridDim.x * blockDim.x) >> 6;
    for (int r = wave; r < nrec; r += nw) {
        int e  = slist[r];
        int d_ = dst[e];
        int g1 = gid[e], g0 = gid[e - 1];
        int lo = e - 1;
        while (lo > 0 && dst[lo - 1] == d_) --lo;
        float invd = 1.0f / den[d_];
        float acc = 0.0f;
        for (int ee = lo; ee < e; ++ee)
            acc += feats[(size_t)ee * 64 + lane] * (exbuf[ee] * invd);
        atomicAdd(&hg[g0 * 64 + lane],  acc);
        atomicAdd(&hg[g1 * 64 + lane], -acc);
    }
}

// ---------------- pass3: weights output ----------------
__global__ __launch_bounds__(256) void weights_kernel(
        const float* __restrict__ exbuf, const float* __restrict__ den,
        const int* __restrict__ dst, float* __restrict__ wout) {
    int i = blockIdx.x * blockDim.x + threadIdx.x;
    if (i < E_TOTAL) wout[i] = exbuf[i] / den[dst[i]];
}

extern "C" void kernel_launch(void* const* d_in, const int* in_sizes, int n_in,
                              void* d_out, int out_size, void* d_ws, size_t ws_size,
                              hipStream_t stream) {
    const float* feats = (const float*)d_in[0];
    const float* W     = (const float*)d_in[1];
    const float* b     = (const float*)d_in[2];
    const int*   dst   = (const int*)d_in[3];
    const int*   gid   = (const int*)d_in[4];

    float* out  = (float*)d_out;
    float* hg   = out;                   // [128,64]
    float* wout = out + NG * FF;         // [E,1]

    float* T     = (float*)d_ws;         // NN*64 floats
    float* exbuf = T + (size_t)NN * 64;  // E floats
    float* den   = exbuf + E_TOTAL;      // NN floats
    int*   nodeg = (int*)(den + NN);     // NN ints
    int*   scount = nodeg + NN;          // 1 int
    int*   slist  = scount + 1;          // MAXSTRAD ints

    init_kernel<<<(NN * 64 + 255) / 256, 256, 0, stream>>>(T, den, nodeg, hg, scount);
    pass1_kernel<<<2048, 256, 0, stream>>>((const float4*)feats, (const float4*)W,
                                           b, dst, gid, exbuf, den, T, nodeg,
                                           scount, slist);
    pass2a_kernel<<<512, 256, 0, stream>>>((const float4*)T, den, nodeg, hg);
    pass2b_kernel<<<4, 256, 0, stream>>>(feats, exbuf, den, dst, gid,
                                         scount, slist, hg);
    weights_kernel<<<(E_TOTAL + 255) / 256, 256, 0, stream>>>(exbuf, den, dst, wout);
}